// Round 16
// baseline (142.432 us; speedup 1.0000x reference)
//
#include <hip/hip_runtime.h>

// Problem constants (from reference)
#define BATCH 16
#define NENT  512
#define D_IN  256
#define D_OUT 32
#define CSP   64
#define COUT  96        // 64 spatial + 32 scatter channels
#define HWDIM 256
#define HWSZ  65536     // 256*256
#define HW4   16384     // HWSZ/4  (2^14)
#define SP_B4  (CSP * HW4)    // 2^20 float4: spatial part per batch
#define SC_B4  (D_OUT * HW4)  // 2^19 float4: scatter part per batch
#define OUT_B4 (COUT * HW4)   // float4 per batch in out
#define PER    (2048 * 256)   // float4 per grid slice (= 2^19)

// clang-native 16B vector types
typedef float vfloat4 __attribute__((ext_vector_type(4)));
typedef int   vint4   __attribute__((ext_vector_type(4)));

// K1: merged prologue, one dispatch, 528 blocks x 512.
//  blocks 0..15  : batch b owner lifecycle — zero the 64 KB batch region,
//                  __syncthreads, atomicMax(n+1) for its 512 entities.
//  blocks 16..527: projection, 512 threads each -> projbuf[b,n,e]
__global__ __launch_bounds__(512)
void prologue_kernel(const float* __restrict__ emb,
                     const float* __restrict__ Wp,
                     const float* __restrict__ bp,
                     const int* __restrict__ loc,
                     int* __restrict__ owner,
                     float* __restrict__ projbuf) {
    int bid = blockIdx.x;
    int tid = threadIdx.x;
    if (bid < BATCH) {
        vint4* ow4 = (vint4*)(owner + bid * HWSZ);
        vint4 z = {0, 0, 0, 0};
        #pragma unroll
        for (int k = 0; k < 32; ++k) {
            ow4[tid + k * 512] = z;
        }
        __syncthreads();
        int ent = bid * NENT + tid;                    // tid == n
        int h = min(max(loc[ent * 2 + 0], 0), HWDIM - 1);
        int w = min(max(loc[ent * 2 + 1], 0), HWDIM - 1);
        atomicMax(&owner[bid * HWSZ + h * HWDIM + w], tid + 1);
        return;
    }
    int gid = (bid - BATCH) * 512 + tid;               // 0 .. 262,143
    int ent = gid >> 5;                                // entity 0..8191
    int e   = gid & 31;                                // feature 0..31
    const vfloat4* er4 = (const vfloat4*)(emb + (size_t)ent * D_IN);
    float acc = bp[e];
    #pragma unroll 8
    for (int d4 = 0; d4 < D_IN / 4; ++d4) {
        vfloat4 ev = er4[d4];                          // bcast in 32-lane grp
        int d = d4 * 4;
        acc += ev.x * Wp[(d + 0) * D_OUT + e];         // coalesced, L1-hot
        acc += ev.y * Wp[(d + 1) * D_OUT + e];
        acc += ev.z * Wp[(d + 2) * D_OUT + e];
        acc += ev.w * Wp[(d + 3) * D_OUT + e];
    }
    projbuf[gid] = acc;                                // coalesced
}

// K2: all output streams in ONE launch, block-level role mixing.
// grid (2048, 48); every thread moves exactly one float4 (one-shot shape).
// A/B vs R13: stores are PLAIN (like the 7 TB/s rocclr fills), loads nt.
__global__ __launch_bounds__(256)
void streams_kernel(const vfloat4* __restrict__ sp,
                    const vint4* __restrict__ owner4,
                    const float* __restrict__ projbuf,
                    vfloat4* __restrict__ out) {
    int t = blockIdx.x * blockDim.x + threadIdx.x;     // 0 .. PER-1
    int s = blockIdx.y;                                // slice 0..47
    int r3 = s - (s / 3) * 3;
    if (r3 != 2) {
        // copy slice c in [0,32): b = c>>1, segment = c&1
        int c   = (s / 3) * 2 + r3;
        int b   = c >> 1;
        int seg = c & 1;
        size_t off = (size_t)seg * PER + t;
        vfloat4 v = __builtin_nontemporal_load(&sp[(size_t)b * SP_B4 + off]);
        out[(size_t)b * OUT_B4 + off] = v;             // plain store
    } else {
        // fill slice: b = s/3
        int b   = s / 3;
        int e   = t >> 14;                             // channel 0..31
        int hw4 = t & (HW4 - 1);
        vint4 ow = owner4[b * HW4 + hw4];              // shared by 32 e-threads
        const float* pb = projbuf + b * (NENT * D_OUT) + e;
        float vx = pb[max(ow.x - 1, 0) * D_OUT];       // speculative, clamped
        float vy = pb[max(ow.y - 1, 0) * D_OUT];
        float vz = pb[max(ow.z - 1, 0) * D_OUT];
        float vw = pb[max(ow.w - 1, 0) * D_OUT];
        vfloat4 v;
        v.x = ow.x ? vx : 0.f;
        v.y = ow.y ? vy : 0.f;
        v.z = ow.z ? vz : 0.f;
        v.w = ow.w ? vw : 0.f;
        out[(size_t)b * OUT_B4 + SP_B4 + t] = v;       // plain store
    }
}

extern "C" void kernel_launch(void* const* d_in, const int* in_sizes, int n_in,
                              void* d_out, int out_size, void* d_ws, size_t ws_size,
                              hipStream_t stream) {
    const float* spatial = (const float*)d_in[0];   // [16,64,256,256]
    const float* emb     = (const float*)d_in[1];   // [16,512,256]
    const float* Wp      = (const float*)d_in[2];   // [256,32]
    const float* bp      = (const float*)d_in[3];   // [32]
    const int*   loc     = (const int*)d_in[4];     // [16,512,2]
    float* out = (float*)d_out;                     // [16,96,256,256]

    int*   owner   = (int*)d_ws;                                         // 4 MB
    float* projbuf = (float*)((char*)d_ws + BATCH * HWSZ * sizeof(int)); // 1 MB

    // K1: owner lifecycle + projection (one dispatch)
    prologue_kernel<<<BATCH + 512, 512, 0, stream>>>(emb, Wp, bp, loc,
                                                     owner, projbuf);
    // K2: all 96 output channels in one launch (block-level stream mixing)
    dim3 grid(2048, 48);
    streams_kernel<<<grid, 256, 0, stream>>>((const vfloat4*)spatial,
                                             (const vint4*)owner, projbuf,
                                             (vfloat4*)out);
}

// Round 17
// 132.181 us; speedup vs baseline: 1.0776x; 1.0776x over previous
//
#include <hip/hip_runtime.h>

// Problem constants (from reference)
#define BATCH 16
#define NENT  512
#define D_IN  256
#define D_OUT 32
#define CSP   64
#define COUT  96        // 64 spatial + 32 scatter channels
#define HWDIM 256
#define HWSZ  65536     // 256*256
#define HW4   16384     // HWSZ/4  (2^14)
#define SP_B4  (CSP * HW4)    // 2^20 float4: spatial part per batch
#define SC_B4  (D_OUT * HW4)  // 2^19 float4: scatter part per batch
#define OUT_B4 (COUT * HW4)   // float4 per batch in out
#define PER    (2048 * 256)   // float4 per grid slice (= 2^19)

// clang-native 16B vector types (accepted by __builtin_nontemporal_*)
typedef float vfloat4 __attribute__((ext_vector_type(4)));
typedef int   vint4   __attribute__((ext_vector_type(4)));

// K1: merged prologue, one dispatch, 528 blocks x 512.
//  blocks 0..15  : batch b owner lifecycle — zero the 64 KB batch region,
//                  __syncthreads, atomicMax(n+1) for its 512 entities.
//                  Batch regions are block-private -> no race.
//  blocks 16..527: projection, 512 threads each -> projbuf[b,n,e]
__global__ __launch_bounds__(512)
void prologue_kernel(const float* __restrict__ emb,
                     const float* __restrict__ Wp,
                     const float* __restrict__ bp,
                     const int* __restrict__ loc,
                     int* __restrict__ owner,
                     float* __restrict__ projbuf) {
    int bid = blockIdx.x;
    int tid = threadIdx.x;
    if (bid < BATCH) {
        vint4* ow4 = (vint4*)(owner + bid * HWSZ);
        vint4 z = {0, 0, 0, 0};
        #pragma unroll
        for (int k = 0; k < 32; ++k) {
            ow4[tid + k * 512] = z;
        }
        __syncthreads();
        int ent = bid * NENT + tid;                    // tid == n
        int h = min(max(loc[ent * 2 + 0], 0), HWDIM - 1);
        int w = min(max(loc[ent * 2 + 1], 0), HWDIM - 1);
        atomicMax(&owner[bid * HWSZ + h * HWDIM + w], tid + 1);
        return;
    }
    int gid = (bid - BATCH) * 512 + tid;               // 0 .. 262,143
    int ent = gid >> 5;                                // entity 0..8191
    int e   = gid & 31;                                // feature 0..31
    const vfloat4* er4 = (const vfloat4*)(emb + (size_t)ent * D_IN);
    float acc = bp[e];
    #pragma unroll 8
    for (int d4 = 0; d4 < D_IN / 4; ++d4) {
        vfloat4 ev = er4[d4];                          // bcast in 32-lane grp
        int d = d4 * 4;
        acc += ev.x * Wp[(d + 0) * D_OUT + e];         // coalesced, L1-hot
        acc += ev.y * Wp[(d + 1) * D_OUT + e];
        acc += ev.z * Wp[(d + 2) * D_OUT + e];
        acc += ev.w * Wp[(d + 3) * D_OUT + e];
    }
    projbuf[gid] = acc;                                // coalesced
}

// K2: all output streams in ONE launch, block-level role mixing.
// grid (2048, 48); every thread moves exactly one float4 (one-shot shape).
// y%3 in {0,1}: copy slice  (32 total: 2^24 float4 spatial -> out[:, :64])
// y%3 == 2   : fill slice   (16 total: 2^23 float4 of out[:, 64:96])
// nt loads + nt stores (best measured combination).
__global__ __launch_bounds__(256)
void streams_kernel(const vfloat4* __restrict__ sp,
                    const vint4* __restrict__ owner4,
                    const float* __restrict__ projbuf,
                    vfloat4* __restrict__ out) {
    int t = blockIdx.x * blockDim.x + threadIdx.x;     // 0 .. PER-1
    int s = blockIdx.y;                                // slice 0..47
    int r3 = s - (s / 3) * 3;
    if (r3 != 2) {
        // copy slice c in [0,32): b = c>>1, segment = c&1
        int c   = (s / 3) * 2 + r3;
        int b   = c >> 1;
        int seg = c & 1;
        size_t off = (size_t)seg * PER + t;
        vfloat4 v = __builtin_nontemporal_load(&sp[(size_t)b * SP_B4 + off]);
        __builtin_nontemporal_store(v, &out[(size_t)b * OUT_B4 + off]);
    } else {
        // fill slice: b = s/3
        int b   = s / 3;
        int e   = t >> 14;                             // channel 0..31
        int hw4 = t & (HW4 - 1);
        vint4 ow = owner4[b * HW4 + hw4];              // shared by 32 e-threads
        const float* pb = projbuf + b * (NENT * D_OUT) + e;
        float vx = pb[max(ow.x - 1, 0) * D_OUT];       // speculative, clamped
        float vy = pb[max(ow.y - 1, 0) * D_OUT];
        float vz = pb[max(ow.z - 1, 0) * D_OUT];
        float vw = pb[max(ow.w - 1, 0) * D_OUT];
        vfloat4 v;
        v.x = ow.x ? vx : 0.f;
        v.y = ow.y ? vy : 0.f;
        v.z = ow.z ? vz : 0.f;
        v.w = ow.w ? vw : 0.f;
        __builtin_nontemporal_store(v, &out[(size_t)b * OUT_B4 + SP_B4 + t]);
    }
}

extern "C" void kernel_launch(void* const* d_in, const int* in_sizes, int n_in,
                              void* d_out, int out_size, void* d_ws, size_t ws_size,
                              hipStream_t stream) {
    const float* spatial = (const float*)d_in[0];   // [16,64,256,256]
    const float* emb     = (const float*)d_in[1];   // [16,512,256]
    const float* Wp      = (const float*)d_in[2];   // [256,32]
    const float* bp      = (const float*)d_in[3];   // [32]
    const int*   loc     = (const int*)d_in[4];     // [16,512,2]
    float* out = (float*)d_out;                     // [16,96,256,256]

    int*   owner   = (int*)d_ws;                                         // 4 MB
    float* projbuf = (float*)((char*)d_ws + BATCH * HWSZ * sizeof(int)); // 1 MB

    // K1: owner lifecycle + projection (one dispatch)
    prologue_kernel<<<BATCH + 512, 512, 0, stream>>>(emb, Wp, bp, loc,
                                                     owner, projbuf);
    // K2: all 96 output channels in one launch (block-level stream mixing)
    dim3 grid(2048, 48);
    streams_kernel<<<grid, 256, 0, stream>>>((const vfloat4*)spatial,
                                             (const vint4*)owner, projbuf,
                                             (vfloat4*)out);
}